// Round 2
// baseline (637.959 us; speedup 1.0000x reference)
//
#include <hip/hip_runtime.h>
#include <hip/hip_bf16.h>

// MHA forward: x[4,2048,1024] -> qkv GEMM -> flash attention (transposed
// S^T/O^T formulation, P stays in registers) -> out proj. bf16 MFMA 16x16x32.
//
// R2 changes (theory: attn latency-bound at 2 blocks/CU, VALU-heavy softmax):
//  - flash_attn: single-buffered Vt (LDS 66->49KB) -> 3 blocks/CU.
//  - persistent blocks (768) + global work-stealing counter (no ragged tail).
//  - Q pre-scaled by 0.125*log2(e) in qkv-GEMM epilogue (f32, pre-rounding):
//    softmax score prep is now 1 FMA.
//  - P pack via v_cvt_pk_bf16_f32 (RNE), l-sum in f32.

typedef __attribute__((ext_vector_type(8))) short short8;
typedef __attribute__((ext_vector_type(4))) float f32x4;

#define SCL2E 0.1803368801111204f  /* 0.125 * log2(e) */
#define L2E   1.44269504088896340736f

#define GLD16(g, l)                                                            \
  __builtin_amdgcn_global_load_lds(                                            \
      (const __attribute__((address_space(1))) unsigned int*)(g),              \
      (__attribute__((address_space(3))) unsigned int*)(l), 16, 0, 0)

__device__ __forceinline__ unsigned short f2b(float f) {
  union { float f; unsigned int u; } v; v.f = f;
  unsigned int u = v.u;
  return (unsigned short)((u + 0x7fffu + ((u >> 16) & 1u)) >> 16);
}
__device__ __forceinline__ unsigned int cvt_pk_bf16(float lo, float hi) {
  unsigned int r;
  asm("v_cvt_pk_bf16_f32 %0, %1, %2" : "=v"(r) : "v"(lo), "v"(hi));
  return r;
}

// ---------------- elementwise fp32 -> bf16 (+ work-counter reset) ----------
__global__ void cvt_bf16(const float* __restrict__ in, ushort* __restrict__ out,
                         int n, unsigned int* __restrict__ wcnt) {
  if (blockIdx.x == 0 && threadIdx.x == 0) *wcnt = 0u;
  int i = (blockIdx.x * blockDim.x + threadIdx.x) * 4;
  if (i + 3 < n) {
    float4 f = *(const float4*)(in + i);
    ushort4 o;
    o.x = f2b(f.x); o.y = f2b(f.y); o.z = f2b(f.z); o.w = f2b(f.w);
    *(ushort4*)(out + i) = o;
  }
}

// -------- W[K][N] fp32 -> Wt[N][K] bf16 (64x64 LDS tile transpose) --------
__global__ void transpose_cvt(const float* __restrict__ W, ushort* __restrict__ Wt,
                              int K, int N) {
  __shared__ float tile[64][65];
  int n0 = blockIdx.x * 64, k0 = blockIdx.y * 64;
  int tx = threadIdx.x & 63, ty = threadIdx.x >> 6;  // ty 0..3
#pragma unroll
  for (int i = 0; i < 64; i += 4)
    tile[ty + i][tx] = W[(size_t)(k0 + ty + i) * N + n0 + tx];
  __syncthreads();
#pragma unroll
  for (int i = 0; i < 64; i += 4)
    Wt[(size_t)(n0 + ty + i) * K + k0 + tx] = f2b(tile[tx][ty + i]);
}

// ---------------- GEMM: C[M,N] = A[M,K] @ Bt[N,K]^T + bias ----------------
// QSCALE=1: multiply q-columns (col%192 < 64) by SCL2E after bias (f32,
// before bf16 rounding) so flash_attn's score prep is a single FMA.
template <int OUTF32, int QSCALE>
__global__ __launch_bounds__(256, 2) void gemm_bt_bias(
    const ushort* __restrict__ A, const ushort* __restrict__ Bt,
    const float* __restrict__ bias, void* __restrict__ Cout,
    int M, int N, int K) {
  __shared__ ushort As[128 * 64];
  __shared__ ushort Bs[128 * 64];
  const int lane = threadIdx.x & 63;
  const int wv = threadIdx.x >> 6;
  const int bm = blockIdx.y, bn = blockIdx.x;
  const int wm = wv >> 1, wn = wv & 1;
  f32x4 acc[4][4] = {};
  const size_t arow0 = (size_t)bm * 128;
  const size_t brow0 = (size_t)bn * 128;

  for (int k0 = 0; k0 < K; k0 += 64) {
    __syncthreads();
#pragma unroll
    for (int i = 0; i < 4; ++i) {
      int r = wv * 32 + i * 8 + (lane >> 3);
      const ushort* ga = A + (arow0 + r) * K + k0 + (lane & 7) * 8;
      GLD16(ga, As + (wv * 32 + i * 8) * 64);
      const ushort* gb = Bt + (brow0 + r) * K + k0 + (lane & 7) * 8;
      GLD16(gb, Bs + (wv * 32 + i * 8) * 64);
    }
    __syncthreads();
    short8 af[2][4], bf[2][4];
#pragma unroll
    for (int kf = 0; kf < 2; ++kf)
#pragma unroll
      for (int t = 0; t < 4; ++t) {
        af[kf][t] = *(const short8*)(As + (wm * 64 + t * 16 + (lane & 15)) * 64 +
                                     kf * 32 + (lane >> 4) * 8);
        bf[kf][t] = *(const short8*)(Bs + (wn * 64 + t * 16 + (lane & 15)) * 64 +
                                     kf * 32 + (lane >> 4) * 8);
      }
#pragma unroll
    for (int kf = 0; kf < 2; ++kf)
#pragma unroll
      for (int mt = 0; mt < 4; ++mt)
#pragma unroll
        for (int nt = 0; nt < 4; ++nt)
          acc[mt][nt] = __builtin_amdgcn_mfma_f32_16x16x32_bf16(
              af[kf][mt], bf[kf][nt], acc[mt][nt], 0, 0, 0);
  }
#pragma unroll
  for (int nt = 0; nt < 4; ++nt) {
    int col = bn * 128 + wn * 64 + nt * 16 + (lane & 15);
    float bv = bias[col];
    float scl = (QSCALE && (col % 192) < 64) ? SCL2E : 1.0f;
#pragma unroll
    for (int mt = 0; mt < 4; ++mt) {
      int row0 = bm * 128 + wm * 64 + mt * 16 + (lane >> 4) * 4;
#pragma unroll
      for (int r = 0; r < 4; ++r) {
        float v = acc[mt][nt][r] + bv;
        if (QSCALE) v *= scl;
        if (OUTF32)
          ((float*)Cout)[(size_t)(row0 + r) * N + col] = v;
        else
          ((ushort*)Cout)[(size_t)(row0 + r) * N + col] = f2b(v);
      }
    }
  }
}

// ---------------- flash attention (transposed formulation) ----------------
// qkv bf16 [8192, 3072]; head h: q cols [192h,192h+64) (PRE-SCALED by SCL2E),
// k +64, v +128. Persistent blocks grab (bh,qt) units via atomic counter.
// S^T = K.Q^T -> softmax in-lane; O^T = V^T.P^T (P^T packed in registers).
// Ks double-buffered (GLD16), Vt single-buffered (reg-staged, T14):
// LDS = 49KB -> 3 blocks/CU. 2 barriers per kt.
__global__ __launch_bounds__(256, 3) void flash_attn(
    const ushort* __restrict__ qkv, const float* __restrict__ mask,
    float* __restrict__ values_f, ushort* __restrict__ values_b,
    unsigned int* __restrict__ wcnt) {
  __shared__ ushort Ks[2][128 * 64];   // swizzled rows, double-buffered
  __shared__ ushort Vt[64 * 136];      // V^T, permuted key-columns, stride 136
  __shared__ int wslot;

  const int lane = threadIdx.x & 63;
  const int wv = threadIdx.x >> 6;
  const int c = lane & 15;          // q within mt-tile
  const int g = lane >> 4;          // key quarter-group
  const int swz = (c & 3) << 1;     // read-side chunk xor for Ks

  // V staging mapping: thread -> key pair (K0,K0+1), d-quarter dq
  const int K0 = lane * 2;
  const int dq = wv;
  const int pc0 = ((K0 >> 5) << 5) + (((K0 >> 2) & 3) << 3) +
                  (((K0 >> 4) & 1) << 2) + (K0 & 3);   // permuted column of K0
  const int vdw = pc0 >> 1;                            // dword column
  const int gcol = (((lane & 7) ^ (((lane >> 3) & 3) << 1)) << 3);

  short8 va0, va1, vb0, vb1;        // in-flight V regs for next tile

  auto loadV = [&](size_t rowbase, int qcol, int t) {
    const ushort* vg = qkv + (rowbase + t * 128 + K0) * 3072 + qcol + 128 + dq * 16;
    va0 = *(const short8*)(vg);
    va1 = *(const short8*)(vg + 8);
    vb0 = *(const short8*)(vg + 3072);
    vb1 = *(const short8*)(vg + 3072 + 8);
  };
  auto writeV = [&]() {
    unsigned int* Vdw = (unsigned int*)Vt;
#pragma unroll
    for (int j = 0; j < 8; ++j)
      Vdw[(dq * 16 + j) * 68 + vdw] =
          ((unsigned int)(unsigned short)vb0[j] << 16) | (unsigned short)va0[j];
#pragma unroll
    for (int j = 0; j < 8; ++j)
      Vdw[(dq * 16 + 8 + j) * 68 + vdw] =
          ((unsigned int)(unsigned short)vb1[j] << 16) | (unsigned short)va1[j];
  };
  auto stageK = [&](size_t rowbase, int qcol, int t, ushort* KsD) {
#pragma unroll
    for (int i = 0; i < 4; ++i) {
      int rloc = wv * 32 + i * 8;
      const ushort* gk = qkv + (rowbase + t * 128 + rloc + (lane >> 3)) * 3072 +
                         qcol + 64 + gcol;
      GLD16(gk, KsD + rloc * 64);
    }
  };

  for (;;) {
    if (threadIdx.x == 0) wslot = (int)atomicAdd(wcnt, 1u);
    __syncthreads();                 // also orders prev unit's LDS reads
    const int u = wslot;
    if (u >= 1024) break;
    const int bh = u & 63;           // bh fast: concurrent units share mask qt
    const int qt = u >> 6;
    const int b = bh >> 4, h = bh & 15;
    const size_t rowbase = (size_t)b * 2048;
    const int qcol = h * 192;

    // Q b-frags straight from global (pre-scaled by SCL2E in GEMM epilogue)
    short8 qf[2][2];
#pragma unroll
    for (int mt = 0; mt < 2; ++mt)
#pragma unroll
      for (int kf = 0; kf < 2; ++kf)
        qf[mt][kf] = *(const short8*)(qkv +
            (rowbase + qt * 128 + wv * 32 + mt * 16 + c) * 3072 + qcol +
            kf * 32 + g * 8);

    f32x4 acc[2][4] = {};
    float mst[2] = {-3e38f, -3e38f}, lst[2] = {0.f, 0.f};
    const float* mrow = mask + (size_t)(qt * 128 + wv * 32 + c) * 2048 + g * 4;

    // ---- prologue: stage tile 0 ----
    loadV(rowbase, qcol, 0);
    stageK(rowbase, qcol, 0, Ks[0]);
    writeV();

    for (int kt = 0; kt < 16; ++kt) {
      __syncthreads();               // Ks[cur](kt) + Vt(kt) ready
      const int cur = kt & 1;
      const ushort* KsC = Ks[cur];
      // issue next tile's loads; latency hides under QK/softmax/PV below
      if (kt < 15) {
        loadV(rowbase, qcol, kt + 1);
        stageK(rowbase, qcol, kt + 1, Ks[cur ^ 1]);
      }

      const float* mkt = mrow + kt * 128;
      // mask for mt=0 issued early (overlaps QK MFMAs)
      float4 msk0[8];
#pragma unroll
      for (int nt = 0; nt < 8; ++nt) msk0[nt] = *(const float4*)(mkt + nt * 16);

      // ---- S^T = K . Q^T ----
      f32x4 sc[2][8];
      __builtin_amdgcn_s_setprio(1);
#pragma unroll
      for (int nt = 0; nt < 8; ++nt) {
        short8 k0 = *(const short8*)(KsC + (nt * 16 + c) * 64 + ((g ^ swz) << 3));
        short8 k1 = *(const short8*)(KsC + (nt * 16 + c) * 64 + (((4 + g) ^ swz) << 3));
        f32x4 z = {0.f, 0.f, 0.f, 0.f};
        sc[0][nt] = __builtin_amdgcn_mfma_f32_16x16x32_bf16(k0, qf[0][0], z, 0, 0, 0);
        sc[0][nt] = __builtin_amdgcn_mfma_f32_16x16x32_bf16(k1, qf[0][1], sc[0][nt], 0, 0, 0);
        sc[1][nt] = __builtin_amdgcn_mfma_f32_16x16x32_bf16(k0, qf[1][0], z, 0, 0, 0);
        sc[1][nt] = __builtin_amdgcn_mfma_f32_16x16x32_bf16(k1, qf[1][1], sc[1][nt], 0, 0, 0);
      }
      __builtin_amdgcn_s_setprio(0);

      // ---- online softmax (in-lane keys, per-lane scalar state) ----
      __attribute__((aligned(16))) unsigned int Dw[2][16];
#pragma unroll
      for (int mt = 0; mt < 2; ++mt) {
        f32x4 t4[8];
#pragma unroll
        for (int nt = 0; nt < 8; ++nt) {
          float4 mk = (mt == 0) ? msk0[nt]
                                : *(const float4*)(mkt + 16 * 2048 + nt * 16);
#pragma unroll
          for (int r = 0; r < 4; ++r)
            t4[nt][r] = fmaf(((const float*)&mk)[r], L2E, sc[mt][nt][r]);
        }
        f32x4 vm = t4[0];
#pragma unroll
        for (int nt = 1; nt < 8; ++nt)
#pragma unroll
          for (int r = 0; r < 4; ++r) vm[r] = fmaxf(vm[r], t4[nt][r]);
        float pm = fmaxf(fmaxf(vm[0], vm[1]), fmaxf(vm[2], vm[3]));
        pm = fmaxf(pm, __shfl_xor(pm, 16));
        pm = fmaxf(pm, __shfl_xor(pm, 32));
        // defer-max (T13): only rescale when running max grew by >8
        if (!__all(pm <= mst[mt] + 8.0f)) {
          float mnew = fmaxf(mst[mt], pm);
          float alpha = exp2f(mst[mt] - mnew);
          mst[mt] = mnew;
          lst[mt] *= alpha;
#pragma unroll
          for (int dt = 0; dt < 4; ++dt)
#pragma unroll
            for (int r = 0; r < 4; ++r) acc[mt][dt][r] *= alpha;
        }
        const float mcur = mst[mt];
        f32x4 rsv = {0.f, 0.f, 0.f, 0.f};
#pragma unroll
        for (int nt = 0; nt < 8; ++nt) {
          float p0 = exp2f(t4[nt][0] - mcur);
          float p1 = exp2f(t4[nt][1] - mcur);
          float p2 = exp2f(t4[nt][2] - mcur);
          float p3 = exp2f(t4[nt][3] - mcur);
          rsv[0] += p0; rsv[1] += p1; rsv[2] += p2; rsv[3] += p3;
          Dw[mt][nt * 2 + 0] = cvt_pk_bf16(p0, p1);
          Dw[mt][nt * 2 + 1] = cvt_pk_bf16(p2, p3);
        }
        float rs = (rsv[0] + rsv[1]) + (rsv[2] + rsv[3]);
        rs += __shfl_xor(rs, 16);
        rs += __shfl_xor(rs, 32);
        lst[mt] += rs;
      }

      // ---- O^T += V^T . P^T  (B-frags are Dw in registers) ----
      const short8* bu0 = (const short8*)Dw[0];
      const short8* bu1 = (const short8*)Dw[1];
      __builtin_amdgcn_s_setprio(1);
#pragma unroll
      for (int dt = 0; dt < 4; ++dt)
#pragma unroll
        for (int kf = 0; kf < 4; ++kf) {
          short8 vf = *(const short8*)(Vt + (dt * 16 + c) * 136 + kf * 32 + g * 8);
          acc[0][dt] = __builtin_amdgcn_mfma_f32_16x16x32_bf16(vf, bu0[kf], acc[0][dt], 0, 0, 0);
          acc[1][dt] = __builtin_amdgcn_mfma_f32_16x16x32_bf16(vf, bu1[kf], acc[1][dt], 0, 0, 0);
        }
      __builtin_amdgcn_s_setprio(0);

      // write next tile's V after all waves finished reading Vt(kt)
      if (kt < 15) {
        __syncthreads();
        writeV();
      }
    }

    // ---- epilogue: O^T col=q (per lane), rows d = dt*16 + g*4 + r ----
#pragma unroll
    for (int mt = 0; mt < 2; ++mt) {
      float rl = 1.0f / lst[mt];
      size_t qrow = rowbase + qt * 128 + wv * 32 + mt * 16 + c;
#pragma unroll
      for (int dt = 0; dt < 4; ++dt) {
        int d0 = h * 64 + dt * 16 + g * 4;
        float4 o;
        o.x = acc[mt][dt][0] * rl; o.y = acc[mt][dt][1] * rl;
        o.z = acc[mt][dt][2] * rl; o.w = acc[mt][dt][3] * rl;
        *(float4*)(values_f + qrow * 1024 + d0) = o;
        ushort4 ob;
        ob.x = f2b(o.x); ob.y = f2b(o.y); ob.z = f2b(o.z); ob.w = f2b(o.w);
        *(ushort4*)(values_b + qrow * 1024 + d0) = ob;
      }
    }
  }
}

extern "C" void kernel_launch(void* const* d_in, const int* in_sizes, int n_in,
                              void* d_out, int out_size, void* d_ws, size_t ws_size,
                              hipStream_t stream) {
  const float* x    = (const float*)d_in[0];
  const float* mask = (const float*)d_in[1];
  const float* Wqkv = (const float*)d_in[2];
  const float* bqkv = (const float*)d_in[3];
  const float* Wo   = (const float*)d_in[4];
  const float* bo   = (const float*)d_in[5];
  float* out      = (float*)d_out;
  float* values_f = out + 8388608;

  char* ws = (char*)d_ws;
  ushort* xb    = (ushort*)(ws + 0);          // 16 MB  [8192,1024] bf16
  ushort* wqkvt = (ushort*)(ws + 16777216);   // 6 MB   [3072,1024] bf16 (W_qkv^T)
  ushort* wot   = (ushort*)(ws + 23068672);   // 2 MB   [1024,1024] bf16 (W_o^T)
  ushort* qkv   = (ushort*)(ws + 25165824);   // 48 MB  [8192,3072] bf16
  ushort* valb  = (ushort*)(ws + 75497472);   // 16 MB  [8192,1024] bf16
  unsigned int* wcnt = (unsigned int*)(ws + 92274688);  // 4 B work counter

  cvt_bf16<<<dim3(8192), dim3(256), 0, stream>>>(x, xb, 8388608, wcnt);
  transpose_cvt<<<dim3(48, 16), dim3(256), 0, stream>>>(Wqkv, wqkvt, 1024, 3072);
  transpose_cvt<<<dim3(16, 16), dim3(256), 0, stream>>>(Wo, wot, 1024, 1024);
  gemm_bt_bias<0, 1><<<dim3(24, 64), dim3(256), 0, stream>>>(
      xb, wqkvt, bqkv, (void*)qkv, 8192, 3072, 1024);
  flash_attn<<<dim3(768), dim3(256), 0, stream>>>(qkv, mask, values_f, valb, wcnt);
  gemm_bt_bias<1, 0><<<dim3(8, 64), dim3(256), 0, stream>>>(
      valb, wot, bo, (void*)out, 8192, 1024, 1024);
}

// Round 4
// 355.724 us; speedup vs baseline: 1.7934x; 1.7934x over previous
//
#include <hip/hip_runtime.h>
#include <hip/hip_bf16.h>

// MHA forward: x[4,2048,1024] -> qkv GEMM -> flash attention (transposed
// S^T/O^T formulation, P stays in registers) -> out proj. bf16 MFMA 16x16x32.
//
// R4 = R3 resubmit (R3 bench was an infra failure; kernel audited for
// hang/fault risks: none). R3 changes vs R1 (462->431us baseline):
//  - static 1024-block grid, __launch_bounds__(256,2) (no allocator coercion);
//    Vt single-buffered keeps LDS at 49.4KB -> HW gives 3 blocks/CU naturally.
//  - keep: Q pre-scaled in GEMM epilogue, cvt_pk_bf16 P-pack, defer-max,
//    setprio, bh-fast block order.
//  - mask zero-tile flags (pre-kernel): skip mask loads+FMAs for
//    all-zero 128x128 mask tiles (exact; general masks take existing path).

typedef __attribute__((ext_vector_type(8))) short short8;
typedef __attribute__((ext_vector_type(4))) float f32x4;

#define SCL2E 0.1803368801111204f  /* 0.125 * log2(e) */
#define L2E   1.44269504088896340736f

#define GLD16(g, l)                                                            \
  __builtin_amdgcn_global_load_lds(                                            \
      (const __attribute__((address_space(1))) unsigned int*)(g),              \
      (__attribute__((address_space(3))) unsigned int*)(l), 16, 0, 0)

__device__ __forceinline__ unsigned short f2b(float f) {
  union { float f; unsigned int u; } v; v.f = f;
  unsigned int u = v.u;
  return (unsigned short)((u + 0x7fffu + ((u >> 16) & 1u)) >> 16);
}
__device__ __forceinline__ unsigned int fbits(float f) {
  union { float f; unsigned int u; } v; v.f = f; return v.u;
}
__device__ __forceinline__ unsigned int cvt_pk_bf16(float lo, float hi) {
  unsigned int r;
  asm("v_cvt_pk_bf16_f32 %0, %1, %2" : "=v"(r) : "v"(lo), "v"(hi));
  return r;
}

// ---------------- elementwise fp32 -> bf16 (+ flag reset) ----------------
__global__ void cvt_bf16(const float* __restrict__ in, ushort* __restrict__ out,
                         int n, unsigned int* __restrict__ mflags) {
  if (blockIdx.x == 0 && threadIdx.x < 16) mflags[threadIdx.x] = 0u;
  int i = (blockIdx.x * blockDim.x + threadIdx.x) * 4;
  if (i + 3 < n) {
    float4 f = *(const float4*)(in + i);
    ushort4 o;
    o.x = f2b(f.x); o.y = f2b(f.y); o.z = f2b(f.z); o.w = f2b(f.w);
    *(ushort4*)(out + i) = o;
  }
}

// ------- mask tile flags: bit kt of mflags[qt] = tile (qt,kt) nonzero -------
__global__ void mask_flags_k(const float* __restrict__ mask,
                             unsigned int* __restrict__ mflags) {
  __shared__ unsigned int s;
  const int qt = blockIdx.x >> 4, kt = blockIdx.x & 15;
  const float* base = mask + (size_t)(qt * 128) * 2048 + kt * 128;
  const int row = threadIdx.x >> 1, col0 = (threadIdx.x & 1) * 64;
  unsigned int acc = 0;
#pragma unroll
  for (int i = 0; i < 16; ++i) {
    float4 f = *(const float4*)(base + (size_t)row * 2048 + col0 + i * 4);
    acc |= fbits(f.x) | fbits(f.y) | fbits(f.z) | fbits(f.w);
  }
  acc &= 0x7fffffffu;  // treat -0.0f as zero
  if (threadIdx.x == 0) s = 0u;
  __syncthreads();
  if (acc) atomicOr(&s, 1u);
  __syncthreads();
  if (threadIdx.x == 0 && s) atomicOr(&mflags[qt], 1u << kt);
}

// -------- W[K][N] fp32 -> Wt[N][K] bf16 (64x64 LDS tile transpose) --------
__global__ void transpose_cvt(const float* __restrict__ W, ushort* __restrict__ Wt,
                              int K, int N) {
  __shared__ float tile[64][65];
  int n0 = blockIdx.x * 64, k0 = blockIdx.y * 64;
  int tx = threadIdx.x & 63, ty = threadIdx.x >> 6;  // ty 0..3
#pragma unroll
  for (int i = 0; i < 64; i += 4)
    tile[ty + i][tx] = W[(size_t)(k0 + ty + i) * N + n0 + tx];
  __syncthreads();
#pragma unroll
  for (int i = 0; i < 64; i += 4)
    Wt[(size_t)(n0 + ty + i) * K + k0 + tx] = f2b(tile[tx][ty + i]);
}

// ---------------- GEMM: C[M,N] = A[M,K] @ Bt[N,K]^T + bias ----------------
// QSCALE=1: multiply q-columns (col%192 < 64) by SCL2E after bias (f32,
// before bf16 rounding) so flash_attn's score prep is a single add.
template <int OUTF32, int QSCALE>
__global__ __launch_bounds__(256, 2) void gemm_bt_bias(
    const ushort* __restrict__ A, const ushort* __restrict__ Bt,
    const float* __restrict__ bias, void* __restrict__ Cout,
    int M, int N, int K) {
  __shared__ ushort As[128 * 64];
  __shared__ ushort Bs[128 * 64];
  const int lane = threadIdx.x & 63;
  const int wv = threadIdx.x >> 6;
  const int bm = blockIdx.y, bn = blockIdx.x;
  const int wm = wv >> 1, wn = wv & 1;
  f32x4 acc[4][4] = {};
  const size_t arow0 = (size_t)bm * 128;
  const size_t brow0 = (size_t)bn * 128;

  for (int k0 = 0; k0 < K; k0 += 64) {
    __syncthreads();
#pragma unroll
    for (int i = 0; i < 4; ++i) {
      int r = wv * 32 + i * 8 + (lane >> 3);
      const ushort* ga = A + (arow0 + r) * K + k0 + (lane & 7) * 8;
      GLD16(ga, As + (wv * 32 + i * 8) * 64);
      const ushort* gb = Bt + (brow0 + r) * K + k0 + (lane & 7) * 8;
      GLD16(gb, Bs + (wv * 32 + i * 8) * 64);
    }
    __syncthreads();
    short8 af[2][4], bf[2][4];
#pragma unroll
    for (int kf = 0; kf < 2; ++kf)
#pragma unroll
      for (int t = 0; t < 4; ++t) {
        af[kf][t] = *(const short8*)(As + (wm * 64 + t * 16 + (lane & 15)) * 64 +
                                     kf * 32 + (lane >> 4) * 8);
        bf[kf][t] = *(const short8*)(Bs + (wn * 64 + t * 16 + (lane & 15)) * 64 +
                                     kf * 32 + (lane >> 4) * 8);
      }
#pragma unroll
    for (int kf = 0; kf < 2; ++kf)
#pragma unroll
      for (int mt = 0; mt < 4; ++mt)
#pragma unroll
        for (int nt = 0; nt < 4; ++nt)
          acc[mt][nt] = __builtin_amdgcn_mfma_f32_16x16x32_bf16(
              af[kf][mt], bf[kf][nt], acc[mt][nt], 0, 0, 0);
  }
#pragma unroll
  for (int nt = 0; nt < 4; ++nt) {
    int col = bn * 128 + wn * 64 + nt * 16 + (lane & 15);
    float bv = bias[col];
    float scl = (QSCALE && (col % 192) < 64) ? SCL2E : 1.0f;
#pragma unroll
    for (int mt = 0; mt < 4; ++mt) {
      int row0 = bm * 128 + wm * 64 + mt * 16 + (lane >> 4) * 4;
#pragma unroll
      for (int r = 0; r < 4; ++r) {
        float v = acc[mt][nt][r] + bv;
        if (QSCALE) v *= scl;
        if (OUTF32)
          ((float*)Cout)[(size_t)(row0 + r) * N + col] = v;
        else
          ((ushort*)Cout)[(size_t)(row0 + r) * N + col] = f2b(v);
      }
    }
  }
}

// ---------------- flash attention (transposed formulation) ----------------
// qkv bf16 [8192, 3072]; head h: q cols [192h,192h+64) (PRE-SCALED by SCL2E),
// k +64, v +128. Block = (b,h,qtile of 128 rows), bh-fast block order.
// S^T = K.Q^T -> softmax in-lane; O^T = V^T.P^T (P^T packed in registers).
// Ks double-buffered (GLD16), Vt single-buffered (reg-staged, T14 split):
// LDS = 49.4KB -> 3 blocks/CU at ~110 VGPR. 2 barriers per kt.
__global__ __launch_bounds__(256, 2) void flash_attn(
    const ushort* __restrict__ qkv, const float* __restrict__ mask,
    const unsigned int* __restrict__ mflags,
    float* __restrict__ values_f, ushort* __restrict__ values_b) {
  __shared__ ushort Ks[2][128 * 64];   // swizzled rows, double-buffered
  __shared__ ushort Vt[64 * 136];      // V^T, permuted key-columns, stride 136

  const int lane = threadIdx.x & 63;
  const int wv = threadIdx.x >> 6;
  const int c = lane & 15;          // q within mt-tile
  const int g = lane >> 4;          // key quarter-group
  const int bh = blockIdx.x & 63;   // bh FAST: concurrent blocks share mask qt
  const int qt = blockIdx.x >> 6;
  const int b = bh >> 4, h = bh & 15;
  const size_t rowbase = (size_t)b * 2048;
  const int qcol = h * 192;
  const int swz = (c & 3) << 1;     // read-side chunk xor for Ks
  const unsigned int flbits = mflags[qt];

  // Q b-frags straight from global (pre-scaled by SCL2E in GEMM epilogue)
  short8 qf[2][2];
#pragma unroll
  for (int mt = 0; mt < 2; ++mt)
#pragma unroll
    for (int kf = 0; kf < 2; ++kf)
      qf[mt][kf] = *(const short8*)(qkv +
          (rowbase + qt * 128 + wv * 32 + mt * 16 + c) * 3072 + qcol +
          kf * 32 + g * 8);

  f32x4 acc[2][4] = {};
  float mst[2] = {-3e38f, -3e38f}, lst[2] = {0.f, 0.f};

  // V staging mapping: thread -> key pair (K0,K0+1), d-quarter dq
  const int K0 = lane * 2;
  const int dq = wv;
  const int pc0 = ((K0 >> 5) << 5) + (((K0 >> 2) & 3) << 3) +
                  (((K0 >> 4) & 1) << 2) + (K0 & 3);   // permuted column of K0
  const int vdw = pc0 >> 1;                            // dword column
  const int gcol = (((lane & 7) ^ (((lane >> 3) & 3) << 1)) << 3);

  short8 va0, va1, vb0, vb1;        // in-flight V regs for next tile

  auto loadV = [&](int t) {
    const ushort* vg = qkv + (rowbase + t * 128 + K0) * 3072 + qcol + 128 + dq * 16;
    va0 = *(const short8*)(vg);
    va1 = *(const short8*)(vg + 8);
    vb0 = *(const short8*)(vg + 3072);
    vb1 = *(const short8*)(vg + 3072 + 8);
  };
  auto writeV = [&]() {
    unsigned int* Vdw = (unsigned int*)Vt;
#pragma unroll
    for (int j = 0; j < 8; ++j)
      Vdw[(dq * 16 + j) * 68 + vdw] =
          ((unsigned int)(unsigned short)vb0[j] << 16) | (unsigned short)va0[j];
#pragma unroll
    for (int j = 0; j < 8; ++j)
      Vdw[(dq * 16 + 8 + j) * 68 + vdw] =
          ((unsigned int)(unsigned short)vb1[j] << 16) | (unsigned short)va1[j];
  };
  auto stageK = [&](int t, ushort* KsD) {
#pragma unroll
    for (int i = 0; i < 4; ++i) {
      int rloc = wv * 32 + i * 8;
      const ushort* gk = qkv + (rowbase + t * 128 + rloc + (lane >> 3)) * 3072 +
                         qcol + 64 + gcol;
      GLD16(gk, KsD + rloc * 64);
    }
  };

  const float* mrow = mask + (size_t)(qt * 128 + wv * 32 + c) * 2048 + g * 4;

  // ---- prologue: stage tile 0 ----
  loadV(0);
  stageK(0, Ks[0]);
  writeV();

  for (int kt = 0; kt < 16; ++kt) {
    __syncthreads();               // Ks[cur](kt) + Vt(kt) ready
    const int cur = kt & 1;
    const ushort* KsC = Ks[cur];
    // issue next tile's loads; latency hides under QK/softmax/PV below
    if (kt < 15) {
      loadV(kt + 1);
      stageK(kt + 1, Ks[cur ^ 1]);
    }

    const bool hasmask = (flbits >> kt) & 1u;
    const float* mkt = mrow + kt * 128;
    // mask for mt=0 issued early (overlaps QK MFMAs); skipped for zero tiles
    float4 msk0[8];
    if (hasmask) {
#pragma unroll
      for (int nt = 0; nt < 8; ++nt) msk0[nt] = *(const float4*)(mkt + nt * 16);
    }

    // ---- S^T = K . Q^T ----
    f32x4 sc[2][8];
    __builtin_amdgcn_s_setprio(1);
#pragma unroll
    for (int nt = 0; nt < 8; ++nt) {
      short8 k0 = *(const short8*)(KsC + (nt * 16 + c) * 64 + ((g ^ swz) << 3));
      short8 k1 = *(const short8*)(KsC + (nt * 16 + c) * 64 + (((4 + g) ^ swz) << 3));
      f32x4 z = {0.f, 0.f, 0.f, 0.f};
      sc[0][nt] = __builtin_amdgcn_mfma_f32_16x16x32_bf16(k0, qf[0][0], z, 0, 0, 0);
      sc[0][nt] = __builtin_amdgcn_mfma_f32_16x16x32_bf16(k1, qf[0][1], sc[0][nt], 0, 0, 0);
      sc[1][nt] = __builtin_amdgcn_mfma_f32_16x16x32_bf16(k0, qf[1][0], z, 0, 0, 0);
      sc[1][nt] = __builtin_amdgcn_mfma_f32_16x16x32_bf16(k1, qf[1][1], sc[1][nt], 0, 0, 0);
    }
    __builtin_amdgcn_s_setprio(0);

    // ---- online softmax (in-lane keys, per-lane scalar state) ----
    __attribute__((aligned(16))) unsigned int Dw[2][16];
#pragma unroll
    for (int mt = 0; mt < 2; ++mt) {
      f32x4 t4[8];
      if (hasmask) {
#pragma unroll
        for (int nt = 0; nt < 8; ++nt) {
          float4 mk = (mt == 0) ? msk0[nt]
                                : *(const float4*)(mkt + 16 * 2048 + nt * 16);
#pragma unroll
          for (int r = 0; r < 4; ++r)
            t4[nt][r] = fmaf(((const float*)&mk)[r], L2E, sc[mt][nt][r]);
        }
      } else {
#pragma unroll
        for (int nt = 0; nt < 8; ++nt) t4[nt] = sc[mt][nt];
      }
      f32x4 vm = t4[0];
#pragma unroll
      for (int nt = 1; nt < 8; ++nt)
#pragma unroll
        for (int r = 0; r < 4; ++r) vm[r] = fmaxf(vm[r], t4[nt][r]);
      float pm = fmaxf(fmaxf(vm[0], vm[1]), fmaxf(vm[2], vm[3]));
      pm = fmaxf(pm, __shfl_xor(pm, 16));
      pm = fmaxf(pm, __shfl_xor(pm, 32));
      // defer-max (T13): only rescale when running max grew by >8
      if (!__all(pm <= mst[mt] + 8.0f)) {
        float mnew = fmaxf(mst[mt], pm);
        float alpha = exp2f(mst[mt] - mnew);
        mst[mt] = mnew;
        lst[mt] *= alpha;
#pragma unroll
        for (int dt = 0; dt < 4; ++dt)
#pragma unroll
          for (int r = 0; r < 4; ++r) acc[mt][dt][r] *= alpha;
      }
      const float mcur = mst[mt];
      f32x4 rsv = {0.f, 0.f, 0.f, 0.f};
#pragma unroll
      for (int nt = 0; nt < 8; ++nt) {
        float p0 = exp2f(t4[nt][0] - mcur);
        float p1 = exp2f(t4[nt][1] - mcur);
        float p2 = exp2f(t4[nt][2] - mcur);
        float p3 = exp2f(t4[nt][3] - mcur);
        rsv[0] += p0; rsv[1] += p1; rsv[2] += p2; rsv[3] += p3;
        Dw[mt][nt * 2 + 0] = cvt_pk_bf16(p0, p1);
        Dw[mt][nt * 2 + 1] = cvt_pk_bf16(p2, p3);
      }
      float rs = (rsv[0] + rsv[1]) + (rsv[2] + rsv[3]);
      rs += __shfl_xor(rs, 16);
      rs += __shfl_xor(rs, 32);
      lst[mt] += rs;
    }

    // ---- O^T += V^T . P^T  (B-frags are Dw in registers) ----
    const short8* bu0 = (const short8*)Dw[0];
    const short8* bu1 = (const short8*)Dw[1];
    __builtin_amdgcn_s_setprio(1);
#pragma unroll
    for (int dt = 0; dt < 4; ++dt)
#pragma unroll
      for (int kf = 0; kf < 4; ++kf) {
        short8 vf = *(const short8*)(Vt + (dt * 16 + c) * 136 + kf * 32 + g * 8);
        acc[0][dt] = __builtin_amdgcn_mfma_f32_16x16x32_bf16(vf, bu0[kf], acc[0][dt], 0, 0, 0);
        acc[1][dt] = __builtin_amdgcn_mfma_f32_16x16x32_bf16(vf, bu1[kf], acc[1][dt], 0, 0, 0);
      }
    __builtin_amdgcn_s_setprio(0);

    // write next tile's V after all waves finished reading Vt(kt);
    // V regs are guaranteed landed (vmcnt drain at this barrier).
    if (kt < 15) {
      __syncthreads();
      writeV();
    }
  }

  // ---- epilogue: O^T col=q (per lane), rows d = dt*16 + g*4 + r ----
#pragma unroll
  for (int mt = 0; mt < 2; ++mt) {
    float rl = 1.0f / lst[mt];
    size_t qrow = rowbase + qt * 128 + wv * 32 + mt * 16 + c;
#pragma unroll
    for (int dt = 0; dt < 4; ++dt) {
      int d0 = h * 64 + dt * 16 + g * 4;
      float4 o;
      o.x = acc[mt][dt][0] * rl; o.y = acc[mt][dt][1] * rl;
      o.z = acc[mt][dt][2] * rl; o.w = acc[mt][dt][3] * rl;
      *(float4*)(values_f + qrow * 1024 + d0) = o;
      ushort4 ob;
      ob.x = f2b(o.x); ob.y = f2b(o.y); ob.z = f2b(o.z); ob.w = f2b(o.w);
      *(ushort4*)(values_b + qrow * 1024 + d0) = ob;
    }
  }
}

extern "C" void kernel_launch(void* const* d_in, const int* in_sizes, int n_in,
                              void* d_out, int out_size, void* d_ws, size_t ws_size,
                              hipStream_t stream) {
  const float* x    = (const float*)d_in[0];
  const float* mask = (const float*)d_in[1];
  const float* Wqkv = (const float*)d_in[2];
  const float* bqkv = (const float*)d_in[3];
  const float* Wo   = (const float*)d_in[4];
  const float* bo   = (const float*)d_in[5];
  float* out      = (float*)d_out;
  float* values_f = out + 8388608;

  char* ws = (char*)d_ws;
  ushort* xb    = (ushort*)(ws + 0);          // 16 MB  [8192,1024] bf16
  ushort* wqkvt = (ushort*)(ws + 16777216);   // 6 MB   [3072,1024] bf16 (W_qkv^T)
  ushort* wot   = (ushort*)(ws + 23068672);   // 2 MB   [1024,1024] bf16 (W_o^T)
  ushort* qkv   = (ushort*)(ws + 25165824);   // 48 MB  [8192,3072] bf16
  ushort* valb  = (ushort*)(ws + 75497472);   // 16 MB  [8192,1024] bf16
  unsigned int* mflg = (unsigned int*)(ws + 92274688);  // 64 B mask tile flags

  cvt_bf16<<<dim3(8192), dim3(256), 0, stream>>>(x, xb, 8388608, mflg);
  mask_flags_k<<<dim3(256), dim3(256), 0, stream>>>(mask, mflg);
  transpose_cvt<<<dim3(48, 16), dim3(256), 0, stream>>>(Wqkv, wqkvt, 1024, 3072);
  transpose_cvt<<<dim3(16, 16), dim3(256), 0, stream>>>(Wo, wot, 1024, 1024);
  gemm_bt_bias<0, 1><<<dim3(24, 64), dim3(256), 0, stream>>>(
      xb, wqkvt, bqkv, (void*)qkv, 8192, 3072, 1024);
  flash_attn<<<dim3(1024), dim3(256), 0, stream>>>(qkv, mask, mflg, values_f, valb);
  gemm_bt_bias<1, 0><<<dim3(8, 64), dim3(256), 0, stream>>>(
      valb, wot, bo, (void*)out, 8192, 1024, 1024);
}